// Round 19
// baseline (165.902 us; speedup 1.0000x reference)
//
#include <hip/hip_runtime.h>
#include <hip/hip_bf16.h>
#include <stdint.h>

#define BATCH 8192
#define PEP 15
#define INC 512
#define OUTC 512
#define XROW (PEP*INC)          // 7680 floats per batch row
#define WT_P_ELEMS (INC*OUTC)   // 262144 bf16 per p
#define NSTEPS 8                // K = 512 = 8 x 64

typedef float f32x4 __attribute__((ext_vector_type(4)));
typedef short s16x8 __attribute__((ext_vector_type(8)));
typedef unsigned int u32x4 __attribute__((ext_vector_type(4)));

__device__ __forceinline__ ushort f2b(float v) {
  // round-to-nearest-even fp32 -> bf16 (prep kernel)
  uint u = __float_as_uint(v);
  u += 0x7fffu + ((u >> 16) & 1u);
  return (ushort)(u >> 16);
}

__device__ __forceinline__ uint cvtpk(float a, float b) {
  // D[15:0]=bf16(a), D[31:16]=bf16(b); RNE. No builtin on gfx950 (T12 recipe).
  uint r;
  asm("v_cvt_pk_bf16_f32 %0, %1, %2" : "=v"(r) : "v"(a), "v"(b));
  return r;
}

// ---------------- kernel 1: W [p][k][n] fp32 -> fragment-linear bf16 (16x16x32) -------
// wt[(((p*16+ks32)*32+n16)*64+l)*8+e] = bf16(W[p][ks32*32+(l>>4)*8+e][n16*16+(l&15)])
// k32-granular; BK=64 consumes pairs (ks32 = ks64*2 + ksub). Verified R1-R17.
__global__ __launch_bounds__(256) void wt_kernel(const float* __restrict__ w,
                                                 ushort* __restrict__ wt) {
  int gid = blockIdx.x * 256 + threadIdx.x;   // 15*16*32*64 = 491520 exactly
  int l   = gid & 63;
  int n16 = (gid >> 6) & 31;
  int ks  = (gid >> 11) & 15;
  int p   = gid >> 15;
  int fr = l & 15, g = l >> 4;
  const float* src = w + (size_t)p * WT_P_ELEMS + (size_t)(ks * 32 + g * 8) * OUTC + n16 * 16 + fr;
  s16x8 hv;
#pragma unroll
  for (int e = 0; e < 8; ++e) hv[e] = (short)f2b(src[(size_t)e * OUTC]);
  *(s16x8*)(wt + (size_t)gid * 8) = hv;
}

// ---------------- kernel 2: BM=256 x BN=256 x BK=64, 16-wave block, 128KB dyn LDS -----
// Slot-count attack: 960 blocks, 1 resident/CU (16 waves = full reg file), 8 K-steps
// -> 30 sequential wave-iteration slots/CU (halved vs R16's 60). Machinery = R16:
// A reg->cvt_pk->linear ds_write; B global_load_lds fragment-linear; double-buffered;
// ONE __syncthreads per K-step; NT-store epilogue.
__global__ __launch_bounds__(1024, 4) void gemm_kernel(const float* __restrict__ x,
                                                       const ushort* __restrict__ wt,
                                                       const float* __restrict__ bias,
                                                       float* __restrict__ out) {
  extern __shared__ __align__(16) char lds_raw[];           // 128 KB dynamic
  auto Ash = (ushort (*)[16][2][64][8])lds_raw;             // [buf][m16][ksub][lane][e] 64KB
  auto Bsh = (ushort (*)[2][16][64][8])(lds_raw + 65536);   // [buf][ksub][n16][lane][e] 64KB

  const int t    = threadIdx.x;
  const int lane = t & 63;
  const int wid  = t >> 6;        // 0..15
  const int wm   = wid >> 2;      // 0..3 : m-quarter
  const int wn   = wid & 3;       // 0..3 : n-quarter
  const int fr   = lane & 15;
  const int g    = lane >> 4;

  // grid: 960 = 8 xcd * 120; within XCD: j&1 = n-half (adjacent -> x L2-share),
  // then mb fastest (wt slice L2-resident), p slowest.
  const int bid  = blockIdx.x;
  const int xcd  = bid & 7;
  const int j    = bid >> 3;               // 0..119
  const int n2   = j & 1;
  const int pair = xcd * 60 + (j >> 1);    // 0..479 = 32 mb x 15 p
  const int mb   = pair & 31;
  const int p    = pair >> 5;
  const int m0   = mb * 256;

  // ---- A staging: wave wid stages m16-block wid (rows m0+wid*16..+16), both ksubs.
  //      lane (fr,g): row +fr, cols ks*64 + ksub*32 + g*8 ..+8. ds slot == lane.
  const float* asrc = x + (size_t)(m0 + wid * 16 + fr) * XROW + p * INC + g * 8;

  // ---- B DMA: wave wid stages chunks c = wid*2+q (32 chunks = 2 ksub x 16 n16)
  const ushort* wt_p = wt + (size_t)p * WT_P_ELEMS + (size_t)lane * 8;

  f32x4 acc[4][4] = {};             // [m16][nf] for this wave's 64x64 tile (64 AGPR)
  f32x4 pa[2][2];                   // [ksub][half] raw A for next cvt: 16 VGPR

  auto load_pa = [&](int ks) {
#pragma unroll
    for (int ksub = 0; ksub < 2; ++ksub) {
      pa[ksub][0] = *(const f32x4*)(asrc + ks * 64 + ksub * 32);
      pa[ksub][1] = *(const f32x4*)(asrc + ks * 64 + ksub * 32 + 4);
    }
  };
  auto cvt_store = [&](int buf) {
#pragma unroll
    for (int ksub = 0; ksub < 2; ++ksub) {
      u32x4 aw;
      aw[0] = cvtpk(pa[ksub][0][0], pa[ksub][0][1]); aw[1] = cvtpk(pa[ksub][0][2], pa[ksub][0][3]);
      aw[2] = cvtpk(pa[ksub][1][0], pa[ksub][1][1]); aw[3] = cvtpk(pa[ksub][1][2], pa[ksub][1][3]);
      *(u32x4*)&Ash[buf][wid][ksub][lane][0] = aw;
    }
  };
  auto stageB = [&](int ks, int buf) {
#pragma unroll
    for (int q = 0; q < 2; ++q) {
      const int c    = wid * 2 + q;       // 0..31
      const int ksb  = c >> 4;            // 0..1
      const int n16l = c & 15;            // 0..15
      __builtin_amdgcn_global_load_lds(
          (const __attribute__((address_space(1))) void*)
            (wt_p + ((size_t)(ks * 2 + ksb) * 32 + n2 * 16 + n16l) * 512),
          (__attribute__((address_space(3))) void*)(&Bsh[buf][ksb][n16l][lane][0]),
          16, 0, 0);
    }
  };

  // ---- prologue: A(0) -> LDS, B(0) DMA, A(1) -> regs
  load_pa(0);
  cvt_store(0);
  stageB(0, 0);
  load_pa(1);
  __syncthreads();

#pragma unroll
  for (int ks = 0; ks < NSTEPS; ++ks) {
    const int cur = ks & 1;
    const int nxt = cur ^ 1;

    // stage(ks+1): A from pa regs (cvt once), B via DMA
    if (ks + 1 < NSTEPS) {
      cvt_store(nxt);
      stageB(ks + 1, nxt);
    }
    // refill pa for ks+2 (flies through MFMA; drained at barrier)
    if (ks + 2 < NSTEPS) load_pa(ks + 2);

    // ksub-phased fragments + MFMA (keeps <=32 frag VGPR live)
#pragma unroll
    for (int ksub = 0; ksub < 2; ++ksub) {
      s16x8 af[4], bf[4];
#pragma unroll
      for (int i = 0; i < 4; ++i)
        af[i] = *(const s16x8*)&Ash[cur][wm * 4 + i][ksub][lane][0];
#pragma unroll
      for (int nf = 0; nf < 4; ++nf)
        bf[nf] = *(const s16x8*)&Bsh[cur][ksub][wn * 4 + nf][lane][0];
#pragma unroll
      for (int i = 0; i < 4; ++i)
#pragma unroll
        for (int nf = 0; nf < 4; ++nf)
          acc[i][nf] = __builtin_amdgcn_mfma_f32_16x16x32_bf16(af[i], bf[nf], acc[i][nf], 0, 0, 0);
    }

    __syncthreads();   // single drain point per K-step (R14/R16-verified shape)
  }

  // ---- epilogue: wave-private LDS transpose (stride 68) -> NT full-line stores ----
  // C/D layout col=lane&15, row=(lane>>4)*4+r (m89-verified).
  const int n0 = n2 * 256 + wn * 64;
  float bv[4];
#pragma unroll
  for (int nf = 0; nf < 4; ++nf) bv[nf] = bias[p * OUTC + n0 + nf * 16 + fr];

  float* trans = (float*)(lds_raw + wid * 4352);   // 16 x 68 f32 per wave (69.6KB total)
  const int er = lane >> 4;          // 0..3
  const int ec = (lane & 15) * 4;    // 0..60

#pragma unroll
  for (int m16 = 0; m16 < 4; ++m16) {
    __builtin_amdgcn_sched_barrier(0);
#pragma unroll
    for (int nf = 0; nf < 4; ++nf)
#pragma unroll
      for (int r = 0; r < 4; ++r)
        trans[(g * 4 + r) * 68 + nf * 16 + fr] = acc[m16][nf][r] + bv[nf];
    __builtin_amdgcn_sched_barrier(0);
    asm volatile("s_waitcnt lgkmcnt(0)" ::: "memory");
    __builtin_amdgcn_sched_barrier(0);
    float* ob = out + (size_t)(m0 + wm * 64 + m16 * 16) * XROW + p * INC + n0;
#pragma unroll
    for (int pass = 0; pass < 4; ++pass) {
      const int row = pass * 4 + er;
      f32x4 v = *(const f32x4*)&trans[row * 68 + ec];
      __builtin_nontemporal_store(v, (f32x4*)(ob + (size_t)row * XROW + ec));
    }
    __builtin_amdgcn_sched_barrier(0);
    asm volatile("s_waitcnt lgkmcnt(0)" ::: "memory");   // reads landed before overwrite
    __builtin_amdgcn_sched_barrier(0);
  }
}

// ---------------- fallback (only if ws too small): naive fp32 ----------------
__global__ void naive_kernel(const float* __restrict__ x, const float* __restrict__ w,
                             const float* __restrict__ bias, float* __restrict__ out) {
  size_t i = (size_t)blockIdx.x * 256 + threadIdx.x;
  if (i >= (size_t)BATCH * PEP * OUTC) return;
  int o  = (int)(i & (OUTC - 1));
  int pp = (int)((i >> 9) % PEP);
  size_t b = i / ((size_t)PEP * OUTC);
  const float* xr = x + b * XROW + pp * INC;
  const float* wc = w + (size_t)pp * INC * OUTC + o;
  float s = bias[pp * OUTC + o];
  for (int k = 0; k < INC; ++k) s += xr[k] * wc[(size_t)k * OUTC];
  out[i] = s;
}

extern "C" void kernel_launch(void* const* d_in, const int* in_sizes, int n_in,
                              void* d_out, int out_size, void* d_ws, size_t ws_size,
                              hipStream_t stream) {
  const float* x    = (const float*)d_in[0];
  const float* w    = (const float*)d_in[1];
  const float* bias = (const float*)d_in[2];
  float* out = (float*)d_out;

  const size_t wt_bytes = (size_t)PEP * INC * OUTC * sizeof(ushort);  // 7.9 MB
  static int lds_ok = -1;
  if (lds_ok < 0) {
    hipError_t e = hipFuncSetAttribute(reinterpret_cast<const void*>(gemm_kernel),
                                       hipFuncAttributeMaxDynamicSharedMemorySize, 131072);
    lds_ok = (e == hipSuccess) ? 1 : 0;
  }
  if (ws_size >= wt_bytes && lds_ok == 1) {
    wt_kernel<<<1920, 256, 0, stream>>>(w, (ushort*)d_ws);
    gemm_kernel<<<960, 1024, 131072, stream>>>(x, (const ushort*)d_ws, bias, out);
  } else {
    size_t total = (size_t)BATCH * PEP * OUTC;
    naive_kernel<<<(int)((total + 255) / 256), 256, 0, stream>>>(x, w, bias, out);
  }
}

// Round 20
// 148.785 us; speedup vs baseline: 1.1150x; 1.1150x over previous
//
#include <hip/hip_runtime.h>
#include <hip/hip_bf16.h>
#include <stdint.h>

#define BATCH 8192
#define PEP 15
#define INC 512
#define OUTC 512
#define XROW (PEP*INC)          // 7680 floats per batch row
#define WT_P_ELEMS (INC*OUTC)   // 262144 bf16 per p
#define NSTEPS 16               // K = 512 = 16 x 32

typedef float f32x4 __attribute__((ext_vector_type(4)));
typedef short s16x8 __attribute__((ext_vector_type(8)));
typedef unsigned int u32x4 __attribute__((ext_vector_type(4)));

__device__ __forceinline__ ushort f2b(float v) {
  // round-to-nearest-even fp32 -> bf16
  uint u = __float_as_uint(v);
  u += 0x7fffu + ((u >> 16) & 1u);
  return (ushort)(u >> 16);
}

__device__ __forceinline__ uint cvtpk(float a, float b) {
  // D[15:0]=bf16(a), D[31:16]=bf16(b); RNE. No builtin on gfx950 (T12 recipe).
  uint r;
  asm("v_cvt_pk_bf16_f32 %0, %1, %2" : "=v"(r) : "v"(a), "v"(b));
  return r;
}

// ---------------- kernel 1: coalesced W -> fragment-linear bf16 (16x16x32) ------------
// Same output layout as R1-R18 (verified):
// wt[(((p*16+ks)*32+n16)*64+l)*8+e] = bf16(W[p][ks*32+(l>>4)*8+e][n16*16+(l&15)])
// NEW structure: block stages a [32k x 128n] tile of W via fully-coalesced reads
// (each 32-lane group reads 512B contiguous), LDS pitch-133 transpose (2-way max),
// then writes fragment-linear s16x8 (contiguous 1KB per 64 threads).
__global__ __launch_bounds__(256) void wt_kernel(const float* __restrict__ w,
                                                 ushort* __restrict__ wt) {
  __shared__ float tile[32 * 133];   // pitch 133: transpose reads 2-way max
  const int t = threadIdx.x;
  const int bid = blockIdx.x;        // 960 = 15p x 16ks x 4nchunk
  const int nchunk = bid & 3;
  const int ks     = (bid >> 2) & 15;
  const int p      = bid >> 6;

  // read phase: rows k = (t>>5) + i*8, cols (t&31)*4 .. +4  (coalesced f32x4)
  const float* src = w + (size_t)p * WT_P_ELEMS + (size_t)(ks * 32) * OUTC + nchunk * 128;
  const int rk = t >> 5;             // 0..7
  const int rc = (t & 31) * 4;       // 0..124
#pragma unroll
  for (int i = 0; i < 4; ++i) {
    const int k = rk + i * 8;
    f32x4 v = *(const f32x4*)(src + (size_t)k * OUTC + rc);
    *(f32x4*)&tile[k * 133 + rc] = v;
  }
  __syncthreads();

  // write phase: fragment f = t, t+256 (512 fragments): n16 = f>>6, l = f&63.
  // elements e: tile[(l>>4)*8 + e][n16*16 + (l&15)]
  ushort* dst = wt + ((size_t)(p * 16 + ks) * 32 + nchunk * 8) * 512;
#pragma unroll
  for (int h = 0; h < 2; ++h) {
    const int f   = t + h * 256;
    const int n16 = f >> 6;
    const int l   = f & 63;
    const int fr  = l & 15;
    const int g   = l >> 4;
    s16x8 hv;
#pragma unroll
    for (int e = 0; e < 8; ++e)
      hv[e] = (short)f2b(tile[(g * 8 + e) * 133 + n16 * 16 + fr]);
    *(s16x8*)(dst + (size_t)n16 * 512 + l * 8) = hv;
  }
}

// ---------------- kernel 2: R17 GEMM (best measured: 149.1us) — unchanged -------------
// BM=128 x BN=256, 512 thr (8 waves; wave (wm,wn) owns 64m x 64n).
// A: reg->cvt_pk->linear ds_write. B: global_load_lds fragment-linear. Double-buffer,
// ONE __syncthreads per K-step. Epilogue: block-cooperative row assembly -> 1KB NT bursts.
__global__ __launch_bounds__(512, 4) void gemm_kernel(const float* __restrict__ x,
                                                      const ushort* __restrict__ wt,
                                                      const float* __restrict__ bias,
                                                      float* __restrict__ out) {
  __shared__ __align__(16) char lds_raw[49152];   // 48KB: A 2x8KB | B 2x16KB ; epilogue reuse
  typedef ushort AshT[8][64][8];
  typedef ushort BshT[16][64][8];
  AshT* Ash = (AshT*)lds_raw;                    // Ash[buf][m16][lane][e]
  BshT* Bsh = (BshT*)(lds_raw + 16384);          // Bsh[buf][n16][lane][e]

  const int t    = threadIdx.x;
  const int lane = t & 63;
  const int wid  = t >> 6;        // 0..7
  const int wm   = wid >> 2;      // 0..1 : m-half
  const int wn   = wid & 3;       // 0..3 : n-quarter
  const int fr   = lane & 15;
  const int g    = lane >> 4;

  // grid: 1920 = 8 xcd * 240; within XCD: j&1 = n-half (adjacent -> x L2-share),
  // then mb fastest (mb-major keeps wt slice L2-resident), p slowest.
  const int bid  = blockIdx.x;
  const int xcd  = bid & 7;
  const int j    = bid >> 3;               // 0..239
  const int n2   = j & 1;
  const int pair = xcd * 120 + (j >> 1);   // 0..959 = 64 mb x 15 p
  const int mb   = pair & 63;
  const int p    = pair >> 6;
  const int m0   = mb * 128;

  const float* asrc = x + (size_t)(m0 + wid * 16 + fr) * XROW + p * INC + g * 8;
  const ushort* bsrc = wt + (size_t)p * WT_P_ELEMS
                     + (size_t)(n2 * 16 + wid * 2) * 512 + (size_t)lane * 8;

  f32x4 acc[4][4] = {};             // [m16][nf] for this wave's 64x64 tile
  f32x4 pa0, pa1;                   // A staging regs (8 floats)

  auto cvt_store = [&](int buf) {
    u32x4 aw;
    aw[0] = cvtpk(pa0[0], pa0[1]); aw[1] = cvtpk(pa0[2], pa0[3]);
    aw[2] = cvtpk(pa1[0], pa1[1]); aw[3] = cvtpk(pa1[2], pa1[3]);
    *(u32x4*)&Ash[buf][wid][lane][0] = aw;
  };
  auto stageB = [&](int ks, int buf) {
#pragma unroll
    for (int q = 0; q < 2; ++q) {
      __builtin_amdgcn_global_load_lds(
          (const __attribute__((address_space(1))) void*)(bsrc + (size_t)ks * 16384 + q * 512),
          (__attribute__((address_space(3))) void*)(&Bsh[buf][wid * 2 + q][lane][0]),
          16, 0, 0);
    }
  };

  // ---- prologue: A(0) -> LDS, B(0) DMA, A(1) -> regs
  pa0 = *(const f32x4*)(asrc);
  pa1 = *(const f32x4*)(asrc + 4);
  cvt_store(0);
  stageB(0, 0);
  pa0 = *(const f32x4*)(asrc + 32);
  pa1 = *(const f32x4*)(asrc + 36);
  __syncthreads();

#pragma unroll
  for (int ks = 0; ks < NSTEPS; ++ks) {
    const int cur = ks & 1;
    const int nxt = cur ^ 1;

    if (ks + 1 < NSTEPS) {
      cvt_store(nxt);
      stageB(ks + 1, nxt);
    }
    if (ks + 2 < NSTEPS) {
      pa0 = *(const f32x4*)(asrc + (ks + 2) * 32);
      pa1 = *(const f32x4*)(asrc + (ks + 2) * 32 + 4);
    }

    s16x8 af[4];
#pragma unroll
    for (int i = 0; i < 4; ++i)
      af[i] = *(const s16x8*)&Ash[cur][wm * 4 + i][lane][0];

    s16x8 bf[4];
#pragma unroll
    for (int nf = 0; nf < 4; ++nf)
      bf[nf] = *(const s16x8*)&Bsh[cur][wn * 4 + nf][lane][0];

#pragma unroll
    for (int i = 0; i < 4; ++i)
#pragma unroll
      for (int nf = 0; nf < 4; ++nf)
        acc[i][nf] = __builtin_amdgcn_mfma_f32_16x16x32_bf16(af[i], bf[nf], acc[i][nf], 0, 0, 0);

    __syncthreads();   // single drain point per K-step
  }

  // ---- epilogue: block-cooperative row assembly -> 1KB-contiguous NT bursts ----
  // C/D layout col=lane&15, row=(lane>>4)*4+r (m89-verified).
  const int n0q = wn * 64;
  float bv[4];
#pragma unroll
  for (int nf = 0; nf < 4; ++nf) bv[nf] = bias[p * OUTC + n2 * 256 + n0q + nf * 16 + fr];

  float* reg0 = (float*)lds_raw;                 // region[0]: 16 x 260 f32
  float* reg1 = (float*)lds_raw + 16 * 260;      // region[1]
  float* myreg = wm ? reg1 : reg0;
  const float* obase = out + p * INC + n2 * 256 + lane * 4;

#pragma unroll
  for (int s = 0; s < 4; ++s) {
    __builtin_amdgcn_sched_barrier(0);
#pragma unroll
    for (int nf = 0; nf < 4; ++nf)
#pragma unroll
      for (int r = 0; r < 4; ++r)
        myreg[(g * 4 + r) * 260 + n0q + nf * 16 + fr] = acc[s][nf][r] + bv[nf];
    __builtin_amdgcn_sched_barrier(0);
    asm volatile("s_waitcnt lgkmcnt(0)" ::: "memory");
    __builtin_amdgcn_s_barrier();
    __builtin_amdgcn_sched_barrier(0);

#pragma unroll
    for (int pass = 0; pass < 4; ++pass) {
      const int row_id = pass * 8 + wid;        // 0..31
      const int rgn = row_id >> 4;
      const int rw  = row_id & 15;
      f32x4 v = *(const f32x4*)((rgn ? reg1 : reg0) + rw * 260 + lane * 4);
      __builtin_nontemporal_store(v,
          (f32x4*)((float*)obase + (size_t)(m0 + rgn * 64 + s * 16 + rw) * XROW));
    }
    __builtin_amdgcn_sched_barrier(0);
    asm volatile("s_waitcnt lgkmcnt(0)" ::: "memory");
    __builtin_amdgcn_s_barrier();
    __builtin_amdgcn_sched_barrier(0);
  }
}

// ---------------- fallback (only if ws too small): naive fp32 ----------------
__global__ void naive_kernel(const float* __restrict__ x, const float* __restrict__ w,
                             const float* __restrict__ bias, float* __restrict__ out) {
  size_t i = (size_t)blockIdx.x * 256 + threadIdx.x;
  if (i >= (size_t)BATCH * PEP * OUTC) return;
  int o  = (int)(i & (OUTC - 1));
  int pp = (int)((i >> 9) % PEP);
  size_t b = i / ((size_t)PEP * OUTC);
  const float* xr = x + b * XROW + pp * INC;
  const float* wc = w + (size_t)pp * INC * OUTC + o;
  float s = bias[pp * OUTC + o];
  for (int k = 0; k < INC; ++k) s += xr[k] * wc[(size_t)k * OUTC];
  out[i] = s;
}

extern "C" void kernel_launch(void* const* d_in, const int* in_sizes, int n_in,
                              void* d_out, int out_size, void* d_ws, size_t ws_size,
                              hipStream_t stream) {
  const float* x    = (const float*)d_in[0];
  const float* w    = (const float*)d_in[1];
  const float* bias = (const float*)d_in[2];
  float* out = (float*)d_out;

  const size_t wt_bytes = (size_t)PEP * INC * OUTC * sizeof(ushort);  // 7.9 MB
  if (ws_size >= wt_bytes) {
    wt_kernel<<<960, 256, 0, stream>>>(w, (ushort*)d_ws);
    gemm_kernel<<<1920, 512, 0, stream>>>(x, (const ushort*)d_ws, bias, out);
  } else {
    size_t total = (size_t)BATCH * PEP * OUTC;
    naive_kernel<<<(int)((total + 255) / 256), 256, 0, stream>>>(x, w, bias, out);
  }
}